// Round 13
// baseline (93.811 us; speedup 1.0000x reference)
//
#include <hip/hip_runtime.h>
#include <hip/hip_bf16.h>

#define NODES 26
#define NGRAPH 16384
#define EPG 650
#define FH 20
#define GD 520
#define WAVES 8            // waves per block; 1 graph per wave
#define BN_EPS 1e-5f
#define EAF 688            // per-wave LDS floats: 650 ea, dis[26] @ 656; bytes 0..2047 reused as bf16 transpose buf
#define WPACK_BYTES 16384  // 16 frags x 64 lanes x 16 B

typedef __attribute__((ext_vector_type(8))) short short8;
typedef __attribute__((ext_vector_type(16))) float f32x16;

union Frag { unsigned u[4]; short8 v; };

__device__ __forceinline__ unsigned short f2bf(float x) {
    __hip_bfloat16 h = __float2bfloat16(x);
    union { __hip_bfloat16 b; unsigned short s; } cv; cv.b = h; return cv.s;
}
__device__ __forceinline__ unsigned pk2(float lo, float hi) {
    return (unsigned)f2bf(lo) | ((unsigned)f2bf(hi) << 16);
}
__device__ __forceinline__ f32x16 mfma32(short8 a, short8 b, f32x16 c) {
    return __builtin_amdgcn_mfma_f32_32x32x16_bf16(a, b, c, 0, 0, 0);
}

// async global->LDS, 4B per lane: LDS dest = base + lane*4 (HW), global src per-lane
typedef const __attribute__((address_space(1))) unsigned GU;
typedef __attribute__((address_space(3))) unsigned LU;
__device__ __forceinline__ void gload_lds4(const float* gsrc_lane, float* lds_base) {
    __builtin_amdgcn_global_load_lds((GU*)gsrc_lane, (LU*)lds_base, 4, 0, 0);
}

// ---------------------------------------------------------------------------
// prepack: build the 16 packed weight B-frags once into workspace.
// ---------------------------------------------------------------------------
__global__ void prepack(
    const float* __restrict__ w1_0, const float* __restrict__ w1_1,
    const float* __restrict__ w20_0, const float* __restrict__ w20_1,
    const float* __restrict__ w21_0, const float* __restrict__ w21_1,
    const float* __restrict__ w3_0, const float* __restrict__ w3_1,
    short8* __restrict__ wpack)
{
    const int e = blockIdx.x * 64 + threadIdx.x;   // grid 16 x 64
    const int fid = e >> 6, ln = e & 63;
    const int mat = fid >> 1, ks = fid & 1;
    const int cc = ln & 31, hf = ln >> 5;
    const int F = (mat < 2) ? 26 : 20;
    const float* Wp;
    switch (mat) {
        case 0: Wp = w1_0; break;  case 1: Wp = w1_1; break;
        case 2: Wp = w20_0; break; case 3: Wp = w20_1; break;
        case 4: Wp = w21_0; break; case 5: Wp = w21_1; break;
        case 6: Wp = w3_0; break;  default: Wp = w3_1; break;
    }
    Frag f;
#pragma unroll
    for (int t = 0; t < 4; ++t) {
        const int k0 = ks * 16 + hf * 8 + 2 * t;
        float lo = 0.f, hi = 0.f;
        if (cc < FH) {
            if (k0 < F)     lo = Wp[cc * F + k0];
            if (k0 + 1 < F) hi = Wp[cc * F + k0 + 1];
        }
        f.u[t] = pk2(lo, hi);
    }
    wpack[e] = f.v;
}

// ---------------------------------------------------------------------------
// graph_wp: one graph per wave; no barrier. Async LDS staging issued first,
// constants + x-frag packing overlapped under it.
// Layouts (32x32-padded, valid 26 nodes x 20 ch):
//  A-frag (H, L): row = lane&31, k = (lane>>5)*8 + j
//  B-frag (W, P): col = lane&31, k = (lane>>5)*8 + j
//  C-layout (Q,P): col = lane&31, row = (r&3) + 8*(r>>2) + 4*(lane>>5)
// ---------------------------------------------------------------------------
__global__ __launch_bounds__(512, 4) void graph_wp(
    const float* __restrict__ x,
    const float* __restrict__ edge_attr,
    const short8* __restrict__ wpack,
    const float* __restrict__ b1, const float* __restrict__ b20,
    const float* __restrict__ b21, const float* __restrict__ b3,
    const float* __restrict__ bn_g, const float* __restrict__ bn_b,
    const float* __restrict__ bn_m, const float* __restrict__ bn_v,
    float* __restrict__ g_out)
{
    __shared__ float ea[WAVES][EAF];    // wave-private only

    const int tid = threadIdx.x;
    const int wid = tid >> 6;
    const int lane = tid & 63;
    const int half = lane >> 5;
    const int c = lane & 31;

    float* EA = ea[wid];
    float* DIS = EA + 656;
    short* TR = (short*)EA;              // aliases EA[0..512): edge data dead once la built
    const int g = blockIdx.x * WAVES + wid;

    // ---- (1) issue async edge_attr staging FIRST (direct to LDS, no VGPRs) ----
    const float* eag = edge_attr + (size_t)g * EPG;
#pragma unroll
    for (int j = 0; j < 10; ++j)
        gload_lds4(eag + 64 * j + lane, EA + 64 * j);
    if (lane < 10)
        gload_lds4(eag + 640 + lane, EA + 640);

    // ---- (2) overlapped under staging: epilogue constants ----
    float Sc = 0.f, Tc = 0.f, bia[4] = {0.f, 0.f, 0.f, 0.f};
    if (c < FH) {
        const float s = bn_g[c] * rsqrtf(bn_v[c] + BN_EPS);
        Sc = s; Tc = bn_b[c] - bn_m[c] * s;
        bia[0] = b1[c]; bia[1] = b20[c]; bia[2] = b21[c]; bia[3] = b3[c];
    }

    // ---- (3) overlapped under staging: x A-frags (layer 0 input) ----
    Frag ha[2];
    {
        const int n = c;
        if (n < NODES) {
            const float* xr = x + ((size_t)g * NODES + n) * 26;
#pragma unroll
            for (int ks = 0; ks < 2; ++ks) {
#pragma unroll
                for (int t = 0; t < 4; ++t) {
                    const int k0 = ks * 16 + half * 8 + 2 * t;
                    float lo = 0.f, hi = 0.f;
                    if (k0 < 26) {
                        const float2 v = *(const float2*)(xr + k0);
                        lo = v.x; hi = v.y;
                    }
                    ha[ks].u[t] = pk2(lo, hi);
                }
            }
        } else {
            Frag z; z.u[0] = z.u[1] = z.u[2] = z.u[3] = 0;
            ha[0] = z; ha[1] = z;
        }
    }

    // ---- (4) staging must have landed before deg reads LDS ----
    asm volatile("s_waitcnt vmcnt(0)" ::: "memory");

    // ---- deg -> dis ----
    if (lane < NODES) {
        float d = 0.f;
#pragma unroll
        for (int j = 0; j < 25; ++j) d += EA[lane * 25 + j];
        DIS[lane] = (d > 0.f) ? rsqrtf(d) : 0.f;
    }

    // ---- L A-frags: L[n][m] = -A[m][n]*dis[m]*dis[n] (src-major edges) ----
    Frag la[2];
    {
        const int n = c;
        const float dn = (n < NODES) ? DIS[n] : 0.f;
#pragma unroll
        for (int ks = 0; ks < 2; ++ks) {
#pragma unroll
            for (int t = 0; t < 4; ++t) {
                float v2[2];
#pragma unroll
                for (int q = 0; q < 2; ++q) {
                    const int m = ks * 16 + half * 8 + 2 * t + q;
                    float val = 0.f;
                    if (n < NODES && m < NODES && m != n) {
                        const int eidx = m * 25 + n - (n > m ? 1 : 0);
                        val = -EA[eidx] * DIS[m] * dn;
                    }
                    v2[q] = val;
                }
                la[ks].u[t] = pk2(v2[0], v2[1]);
            }
        }
    }

    // ---- 4 layers ----
    float h[16];
#pragma unroll
    for (int L = 0; L < 4; ++L) {
        // weight frags via coalesced global loads (L2/L1-resident, lane*16B)
        const short8* wp = wpack + (size_t)L * 4 * 64;
        Frag wq0, wq1, wp0, wp1;
        wq0.v = wp[lane];
        wq1.v = wp[64 + lane];
        wp0.v = wp[128 + lane];
        wp1.v = wp[192 + lane];

        f32x16 Qc = {};
        f32x16 Pc = {};
        Qc = mfma32(ha[0].v, wq0.v, Qc);
        Pc = mfma32(ha[0].v, wp0.v, Pc);
        Qc = mfma32(ha[1].v, wq1.v, Qc);
        Pc = mfma32(ha[1].v, wp1.v, Pc);

        // P (C-layout) -> B-frags via pack + permlane32_swap (no LDS)
        Frag pb0, pb1;
#pragma unroll
        for (int ks = 0; ks < 2; ++ks) {
            const int b = ks * 8;
            const unsigned u0 = pk2(Pc[b + 0], Pc[b + 1]);
            const unsigned u1 = pk2(Pc[b + 2], Pc[b + 3]);
            const unsigned v0 = pk2(Pc[b + 4], Pc[b + 5]);
            const unsigned v1 = pk2(Pc[b + 6], Pc[b + 7]);
            auto r0 = __builtin_amdgcn_permlane32_swap(u0, v0, false, false);
            auto r1 = __builtin_amdgcn_permlane32_swap(u1, v1, false, false);
            Frag& pb = ks ? pb1 : pb0;
            pb.u[0] = r0[0]; pb.u[2] = r0[1];
            pb.u[1] = r1[0]; pb.u[3] = r1[1];
        }
        Qc = mfma32(la[0].v, pb0.v, Qc);
        Qc = mfma32(la[1].v, pb1.v, Qc);

        // epilogue: bias -> relu -> BN affine -> residual (all f32)
        const float bb = bia[L];
#pragma unroll
        for (int r = 0; r < 16; ++r) {
            float z = fmaxf(Qc[r] + bb, 0.f);
            z = z * Sc + Tc;
            h[r] = L ? fmaf(0.7f, h[r], z) : z;
        }

        if (L < 3) {
            // C-layout -> LDS [node][ch] bf16 (XOR-swizzled) -> next A-frags
#pragma unroll
            for (int r = 0; r < 16; ++r) {
                const int n = (r & 3) + 8 * (r >> 2) + 4 * half;
                const int byte = (n * 64 + 2 * c) ^ ((n & 7) << 4);
                *(short*)((char*)TR + byte) = (short)f2bf(h[r]);
            }
#pragma unroll
            for (int ks = 0; ks < 2; ++ks) {
                const int byte = (c * 64 + ks * 32 + half * 16) ^ ((c & 7) << 4);
                Frag f; f.v = *(const short8*)((const char*)TR + byte);
                ha[ks] = f;
            }
        }
    }

    // ---- emit h4: C-layout -> LDS [node][ch] f32 -> coalesced float4 store ----
#pragma unroll
    for (int r = 0; r < 16; ++r) {
        const int n = (r & 3) + 8 * (r >> 2) + 4 * half;
        if (n < NODES && c < FH) EA[n * FH + c] = h[r];
    }
    {
        const float4* EAv = (const float4*)EA;            // EA 16B-aligned (2752B/wave)
        float4* gov = (float4*)(g_out + (size_t)g * GD);  // 520*4B = 2080, 16B-aligned
#pragma unroll
        for (int jj = 0; jj < 3; ++jj) {
            const int i = lane + 64 * jj;
            if (i < 130) gov[i] = EAv[i];
        }
    }
}

// ---------------------------------------------------------------------------
// graph_fb: round-7 passing kernel VERBATIM — fallback when workspace small.
// ---------------------------------------------------------------------------
template <bool FUSED_FC>
__global__ __launch_bounds__(512, 4) void graph_fb(
    const float* __restrict__ x,
    const float* __restrict__ edge_attr,
    const float* __restrict__ w1_0, const float* __restrict__ w1_1, const float* __restrict__ b1,
    const float* __restrict__ w20_0, const float* __restrict__ w20_1, const float* __restrict__ b20,
    const float* __restrict__ w21_0, const float* __restrict__ w21_1, const float* __restrict__ b21,
    const float* __restrict__ w3_0, const float* __restrict__ w3_1, const float* __restrict__ b3,
    const float* __restrict__ bn_g, const float* __restrict__ bn_b,
    const float* __restrict__ bn_m, const float* __restrict__ bn_v,
    float* __restrict__ g_out,
    const float* __restrict__ fc_w, const float* __restrict__ fc_b)
{
    __shared__ short8 wfrag[16 * 64];
    __shared__ float  ea[WAVES][EAF];

    const int tid = threadIdx.x;
    const int wid = tid >> 6;
    const int lane = tid & 63;
    const int half = lane >> 5;
    const int c = lane & 31;

    for (int e = tid; e < 16 * 64; e += 512) {
        const int fid = e >> 6, ln = e & 63;
        const int mat = fid >> 1, ks = fid & 1;
        const int cc = ln & 31, hf = ln >> 5;
        const int F = (mat < 2) ? 26 : 20;
        const float* Wp;
        switch (mat) {
            case 0: Wp = w1_0; break;  case 1: Wp = w1_1; break;
            case 2: Wp = w20_0; break; case 3: Wp = w20_1; break;
            case 4: Wp = w21_0; break; case 5: Wp = w21_1; break;
            case 6: Wp = w3_0; break;  default: Wp = w3_1; break;
        }
        Frag f;
#pragma unroll
        for (int t = 0; t < 4; ++t) {
            const int k0 = ks * 16 + hf * 8 + 2 * t;
            float lo = 0.f, hi = 0.f;
            if (cc < FH) {
                if (k0 < F)     lo = Wp[cc * F + k0];
                if (k0 + 1 < F) hi = Wp[cc * F + k0 + 1];
            }
            f.u[t] = pk2(lo, hi);
        }
        wfrag[e] = f.v;
    }

    float Sc = 0.f, Tc = 0.f, bia[4] = {0.f, 0.f, 0.f, 0.f};
    if (c < FH) {
        const float s = bn_g[c] * rsqrtf(bn_v[c] + BN_EPS);
        Sc = s; Tc = bn_b[c] - bn_m[c] * s;
        bia[0] = b1[c]; bia[1] = b20[c]; bia[2] = b21[c]; bia[3] = b3[c];
    }

    __syncthreads();

    float* EA = ea[wid];
    float* DIS = EA + 656;
    short* TR = (short*)EA;
    const int g = blockIdx.x * WAVES + wid;

    const float* eag = edge_attr + (size_t)g * EPG;
    for (int i = lane; i < EPG; i += 64) EA[i] = eag[i];

    if (lane < NODES) {
        float d = 0.f;
#pragma unroll
        for (int j = 0; j < 25; ++j) d += EA[lane * 25 + j];
        DIS[lane] = (d > 0.f) ? rsqrtf(d) : 0.f;
    }

    Frag la[2];
    {
        const int n = c;
        const float dn = (n < NODES) ? DIS[n] : 0.f;
#pragma unroll
        for (int ks = 0; ks < 2; ++ks) {
#pragma unroll
            for (int t = 0; t < 4; ++t) {
                float v2[2];
#pragma unroll
                for (int q = 0; q < 2; ++q) {
                    const int m = ks * 16 + half * 8 + 2 * t + q;
                    float val = 0.f;
                    if (n < NODES && m < NODES && m != n) {
                        const int eidx = m * 25 + n - (n > m ? 1 : 0);
                        val = -EA[eidx] * DIS[m] * dn;
                    }
                    v2[q] = val;
                }
                la[ks].u[t] = pk2(v2[0], v2[1]);
            }
        }
    }

    Frag ha[2];
    {
        const int n = c;
        if (n < NODES) {
            const float* xr = x + ((size_t)g * NODES + n) * 26;
#pragma unroll
            for (int ks = 0; ks < 2; ++ks) {
#pragma unroll
                for (int t = 0; t < 4; ++t) {
                    const int k0 = ks * 16 + half * 8 + 2 * t;
                    float lo = 0.f, hi = 0.f;
                    if (k0 < 26) {
                        const float2 v = *(const float2*)(xr + k0);
                        lo = v.x; hi = v.y;
                    }
                    ha[ks].u[t] = pk2(lo, hi);
                }
            }
        } else {
            Frag z; z.u[0] = z.u[1] = z.u[2] = z.u[3] = 0;
            ha[0] = z; ha[1] = z;
        }
    }

    float h[16];
#pragma unroll
    for (int L = 0; L < 4; ++L) {
        Frag wq0, wq1, wp0, wp1;
        wq0.v = wfrag[((L * 2 + 0) * 2 + 0) * 64 + lane];
        wq1.v = wfrag[((L * 2 + 0) * 2 + 1) * 64 + lane];
        wp0.v = wfrag[((L * 2 + 1) * 2 + 0) * 64 + lane];
        wp1.v = wfrag[((L * 2 + 1) * 2 + 1) * 64 + lane];

        f32x16 Qc = {};
        f32x16 Pc = {};
        Qc = mfma32(ha[0].v, wq0.v, Qc);
        Pc = mfma32(ha[0].v, wp0.v, Pc);
        Qc = mfma32(ha[1].v, wq1.v, Qc);
        Pc = mfma32(ha[1].v, wp1.v, Pc);

        Frag pb0, pb1;
#pragma unroll
        for (int ks = 0; ks < 2; ++ks) {
            const int b = ks * 8;
            const unsigned u0 = pk2(Pc[b + 0], Pc[b + 1]);
            const unsigned u1 = pk2(Pc[b + 2], Pc[b + 3]);
            const unsigned v0 = pk2(Pc[b + 4], Pc[b + 5]);
            const unsigned v1 = pk2(Pc[b + 6], Pc[b + 7]);
            auto r0 = __builtin_amdgcn_permlane32_swap(u0, v0, false, false);
            auto r1 = __builtin_amdgcn_permlane32_swap(u1, v1, false, false);
            Frag& pb = ks ? pb1 : pb0;
            pb.u[0] = r0[0]; pb.u[2] = r0[1];
            pb.u[1] = r1[0]; pb.u[3] = r1[1];
        }
        Qc = mfma32(la[0].v, pb0.v, Qc);
        Qc = mfma32(la[1].v, pb1.v, Qc);

        const float bb = bia[L];
#pragma unroll
        for (int r = 0; r < 16; ++r) {
            float z = fmaxf(Qc[r] + bb, 0.f);
            z = z * Sc + Tc;
            h[r] = L ? fmaf(0.7f, h[r], z) : z;
        }

        if (L < 3) {
#pragma unroll
            for (int r = 0; r < 16; ++r) {
                const int n = (r & 3) + 8 * (r >> 2) + 4 * half;
                const int byte = (n * 64 + 2 * c) ^ ((n & 7) << 4);
                *(short*)((char*)TR + byte) = (short)f2bf(h[r]);
            }
#pragma unroll
            for (int ks = 0; ks < 2; ++ks) {
                const int byte = (c * 64 + ks * 32 + half * 16) ^ ((c & 7) << 4);
                Frag f; f.v = *(const short8*)((const char*)TR + byte);
                ha[ks] = f;
            }
        }
    }

#pragma unroll
    for (int r = 0; r < 16; ++r) {
        const int n = (r & 3) + 8 * (r >> 2) + 4 * half;
        if (n < NODES && c < FH) EA[n * FH + c] = h[r];
    }

    if constexpr (!FUSED_FC) {
        float* go = g_out + (size_t)g * GD;
        for (int i = lane; i < GD; i += 64) go[i] = EA[i];
    } else {
#pragma unroll
        for (int oo = 0; oo < 2; ++oo) {
            const int o = lane + oo * 64;
            float dot = fc_b[o];
            const float* wr = fc_w + (size_t)o * GD;
            for (int i = 0; i < GD; ++i) dot = fmaf(EA[i], wr[i], dot);
            g_out[(size_t)g * 128 + o] = dot;
        }
    }
}

// ---------------------------------------------------------------------------
// fc_kernel2: C[16384][128] = G[16384][520] @ fc_w[128][520]^T + fc_b  (f32)
// 32x64 tile, grid 512x2 = 1024 blocks (4/CU -> TLP), double-buffered
// global->reg prefetch. Per-output K-order identical to previous fc.
// ---------------------------------------------------------------------------
#define FBM 32
#define FBN 64
#define FBK 40

__global__ __launch_bounds__(256) void fc_kernel2(
    const float* __restrict__ G, const float* __restrict__ W,
    const float* __restrict__ bias, float* __restrict__ C)
{
    __shared__ float Al[FBK][FBM + 4];   // 40x36 (rows 144B, 16B-aligned)
    __shared__ float Bl[FBK][FBN];       // 40x64

    const int tid = threadIdx.x;
    const int m0 = blockIdx.x * FBM;
    const int n0 = blockIdx.y * FBN;

    const int r0 = (tid >> 4) * 2;       // 0..30 (even)
    const int c0 = (tid & 15) * 4;       // 0..60

    const int arow = tid >> 3;           // 0..31, 5 floats each
    const int aq   = tid & 7;
    const int brow = tid >> 2;           // 0..63, 10 floats each
    const int bh   = tid & 3;

    const float* gaBase = G + (size_t)(m0 + arow) * GD + aq * 5;
    const float* gbBase = W + (size_t)(n0 + brow) * GD + bh * 10;

    float a_pf[5], b_pf[10];
#pragma unroll
    for (int j = 0; j < 5; ++j) a_pf[j] = gaBase[j];
#pragma unroll
    for (int j = 0; j < 10; ++j) b_pf[j] = gbBase[j];

    float acc[2][4] = {};

    for (int kt = 0; kt < GD; kt += FBK) {
        __syncthreads();                 // protect LDS from previous compute
#pragma unroll
        for (int j = 0; j < 5; ++j)  Al[aq * 5 + j][arow] = a_pf[j];
#pragma unroll
        for (int j = 0; j < 10; ++j) Bl[bh * 10 + j][brow] = b_pf[j];
        __syncthreads();

        if (kt + FBK < GD) {             // prefetch next tile during compute
#pragma unroll
            for (int j = 0; j < 5; ++j)  a_pf[j] = gaBase[kt + FBK + j];
#pragma unroll
            for (int j = 0; j < 10; ++j) b_pf[j] = gbBase[kt + FBK + j];
        }

#pragma unroll 8
        for (int k = 0; k < FBK; ++k) {
            const float2 a2 = *reinterpret_cast<const float2*>(&Al[k][r0]);
            const float4 b4 = *reinterpret_cast<const float4*>(&Bl[k][c0]);
            acc[0][0] = fmaf(a2.x, b4.x, acc[0][0]);
            acc[0][1] = fmaf(a2.x, b4.y, acc[0][1]);
            acc[0][2] = fmaf(a2.x, b4.z, acc[0][2]);
            acc[0][3] = fmaf(a2.x, b4.w, acc[0][3]);
            acc[1][0] = fmaf(a2.y, b4.x, acc[1][0]);
            acc[1][1] = fmaf(a2.y, b4.y, acc[1][1]);
            acc[1][2] = fmaf(a2.y, b4.z, acc[1][2]);
            acc[1][3] = fmaf(a2.y, b4.w, acc[1][3]);
        }
    }

    const float4 bb = *reinterpret_cast<const float4*>(&bias[n0 + c0]);
#pragma unroll
    for (int i = 0; i < 2; ++i) {
        float4 o;
        o.x = acc[i][0] + bb.x;
        o.y = acc[i][1] + bb.y;
        o.z = acc[i][2] + bb.z;
        o.w = acc[i][3] + bb.w;
        *reinterpret_cast<float4*>(&C[(size_t)(m0 + r0 + i) * 128 + n0 + c0]) = o;
    }
}

// ---------------------------------------------------------------------------

extern "C" void kernel_launch(void* const* d_in, const int* in_sizes, int n_in,
                              void* d_out, int out_size, void* d_ws, size_t ws_size,
                              hipStream_t stream)
{
    const float* x        = (const float*)d_in[0];
    const float* edge_attr= (const float*)d_in[2];
    const float* w1_0  = (const float*)d_in[4];
    const float* w1_1  = (const float*)d_in[5];
    const float* b1    = (const float*)d_in[6];
    const float* w20_0 = (const float*)d_in[7];
    const float* w20_1 = (const float*)d_in[8];
    const float* b20   = (const float*)d_in[9];
    const float* w21_0 = (const float*)d_in[10];
    const float* w21_1 = (const float*)d_in[11];
    const float* b21   = (const float*)d_in[12];
    const float* w3_0  = (const float*)d_in[13];
    const float* w3_1  = (const float*)d_in[14];
    const float* b3    = (const float*)d_in[15];
    const float* bn_g  = (const float*)d_in[16];
    const float* bn_b  = (const float*)d_in[17];
    const float* bn_m  = (const float*)d_in[18];
    const float* bn_v  = (const float*)d_in[19];
    const float* fc_w  = (const float*)d_in[20];
    const float* fc_b  = (const float*)d_in[21];
    float* out = (float*)d_out;

    const size_t need_g = (size_t)NGRAPH * GD * sizeof(float);

    if (ws_size >= need_g + WPACK_BYTES) {
        short8* wpack = (short8*)d_ws;
        float* gbuf = (float*)((char*)d_ws + WPACK_BYTES);
        hipLaunchKernelGGL(prepack, dim3(16), dim3(64), 0, stream,
                           w1_0, w1_1, w20_0, w20_1, w21_0, w21_1, w3_0, w3_1, wpack);
        hipLaunchKernelGGL(graph_wp, dim3(NGRAPH / WAVES), dim3(512), 0, stream,
                           x, edge_attr, wpack, b1, b20, b21, b3,
                           bn_g, bn_b, bn_m, bn_v, gbuf);
        hipLaunchKernelGGL(fc_kernel2, dim3(NGRAPH / FBM, 128 / FBN), dim3(256), 0, stream,
                           gbuf, fc_w, fc_b, out);
    } else if (ws_size >= need_g) {
        float* gbuf = (float*)d_ws;
        hipLaunchKernelGGL((graph_fb<false>), dim3(NGRAPH / WAVES), dim3(512), 0, stream,
                           x, edge_attr, w1_0, w1_1, b1, w20_0, w20_1, b20,
                           w21_0, w21_1, b21, w3_0, w3_1, b3,
                           bn_g, bn_b, bn_m, bn_v, gbuf, fc_w, fc_b);
        hipLaunchKernelGGL(fc_kernel2, dim3(NGRAPH / FBM, 128 / FBN), dim3(256), 0, stream,
                           gbuf, fc_w, fc_b, out);
    } else {
        hipLaunchKernelGGL((graph_fb<true>), dim3(NGRAPH / WAVES), dim3(512), 0, stream,
                           x, edge_attr, w1_0, w1_1, b1, w20_0, w20_1, b20,
                           w21_0, w21_1, b21, w3_0, w3_1, b3,
                           bn_g, bn_b, bn_m, bn_v, out, fc_w, fc_b);
    }
}

// Round 14
// 66.603 us; speedup vs baseline: 1.4085x; 1.4085x over previous
//
#include <hip/hip_runtime.h>
#include <hip/hip_bf16.h>

#define NODES 26
#define NGRAPH 16384
#define EPG 650
#define FH 20
#define GD 520
#define WAVES 8            // graph kernel: waves per block; 1 graph per wave
#define BN_EPS 1e-5f
#define EAF 688            // per-wave LDS floats: 650 ea, dis[26] @ 656; bytes 0..2047 reused as bf16 transpose buf
#define WPACK_BYTES 16384      // 16 frags x 64 lanes x 16 B (layer weights)
#define WPACK2_ENT 16896       // 33 ksteps x 4 ntiles x 2 (hi,lo) x 64 lanes
#define WPACK2_BYTES (WPACK2_ENT * 16)
#define WS_HDR (WPACK_BYTES + WPACK2_BYTES)   // 286720 B before g buffer

typedef __attribute__((ext_vector_type(8))) short short8;
typedef __attribute__((ext_vector_type(16))) float f32x16;

union Frag { unsigned u[4]; short8 v; };

__device__ __forceinline__ unsigned short f2bf(float x) {
    __hip_bfloat16 h = __float2bfloat16(x);
    union { __hip_bfloat16 b; unsigned short s; } cv; cv.b = h; return cv.s;
}
__device__ __forceinline__ float bf2f(unsigned short s) {
    return __uint_as_float((unsigned)s << 16);
}
__device__ __forceinline__ unsigned pk2(float lo, float hi) {
    return (unsigned)f2bf(lo) | ((unsigned)f2bf(hi) << 16);
}
__device__ __forceinline__ f32x16 mfma32(short8 a, short8 b, f32x16 c) {
    return __builtin_amdgcn_mfma_f32_32x32x16_bf16(a, b, c, 0, 0, 0);
}

// async global->LDS, 4B per lane
typedef const __attribute__((address_space(1))) unsigned GU;
typedef __attribute__((address_space(3))) unsigned LU;
__device__ __forceinline__ void gload_lds4(const float* gsrc_lane, float* lds_base) {
    __builtin_amdgcn_global_load_lds((GU*)gsrc_lane, (LU*)lds_base, 4, 0, 0);
}

// ---------------------------------------------------------------------------
// prepack_all: entries 0..1023 = layer-weight B-frags (wpack);
// entries 1024..18943 = fc_w split-precision B-frags (wpack2).
// wpack2 index: ((sp*4 + nt)*2 + hl)*64 + lane ; col = nt*32 + (lane&31),
// k = sp*16 + (lane>>5)*8 + 2t (+1). hl=0: bf16(w) ; hl=1: bf16(w - bf16(w)).
// ---------------------------------------------------------------------------
__global__ void prepack_all(
    const float* __restrict__ w1_0, const float* __restrict__ w1_1,
    const float* __restrict__ w20_0, const float* __restrict__ w20_1,
    const float* __restrict__ w21_0, const float* __restrict__ w21_1,
    const float* __restrict__ w3_0, const float* __restrict__ w3_1,
    const float* __restrict__ fc_w,
    short8* __restrict__ wpack, short8* __restrict__ wpack2)
{
    const int e = blockIdx.x * 256 + threadIdx.x;   // grid 70 x 256 = 17920
    if (e < 1024) {
        const int fid = e >> 6, ln = e & 63;
        const int mat = fid >> 1, ks = fid & 1;
        const int cc = ln & 31, hf = ln >> 5;
        const int F = (mat < 2) ? 26 : 20;
        const float* Wp;
        switch (mat) {
            case 0: Wp = w1_0; break;  case 1: Wp = w1_1; break;
            case 2: Wp = w20_0; break; case 3: Wp = w20_1; break;
            case 4: Wp = w21_0; break; case 5: Wp = w21_1; break;
            case 6: Wp = w3_0; break;  default: Wp = w3_1; break;
        }
        Frag f;
#pragma unroll
        for (int t = 0; t < 4; ++t) {
            const int k0 = ks * 16 + hf * 8 + 2 * t;
            float lo = 0.f, hi = 0.f;
            if (cc < FH) {
                if (k0 < F)     lo = Wp[cc * F + k0];
                if (k0 + 1 < F) hi = Wp[cc * F + k0 + 1];
            }
            f.u[t] = pk2(lo, hi);
        }
        wpack[e] = f.v;
    } else if (e < 1024 + WPACK2_ENT) {
        const int e2 = e - 1024;
        const int ln = e2 & 63;
        const int fid2 = e2 >> 6;          // 0..263
        const int hl = fid2 & 1;
        const int nt = (fid2 >> 1) & 3;
        const int sp = fid2 >> 3;          // 0..32
        const int o = nt * 32 + (ln & 31);
        const int hf = ln >> 5;
        Frag f;
#pragma unroll
        for (int t = 0; t < 4; ++t) {
            const int k0 = sp * 16 + hf * 8 + 2 * t;
            float a = (k0 < GD)     ? fc_w[(size_t)o * GD + k0]     : 0.f;
            float b = (k0 + 1 < GD) ? fc_w[(size_t)o * GD + k0 + 1] : 0.f;
            if (hl == 0) {
                f.u[t] = pk2(a, b);
            } else {
                const float ra = a - bf2f(f2bf(a));
                const float rb = b - bf2f(f2bf(b));
                f.u[t] = pk2(ra, rb);
            }
        }
        wpack2[e2] = f.v;
    }
}

// ---------------------------------------------------------------------------
// graph_wp: one graph per wave; no barrier (unchanged from round 12/13).
// ---------------------------------------------------------------------------
__global__ __launch_bounds__(512, 4) void graph_wp(
    const float* __restrict__ x,
    const float* __restrict__ edge_attr,
    const short8* __restrict__ wpack,
    const float* __restrict__ b1, const float* __restrict__ b20,
    const float* __restrict__ b21, const float* __restrict__ b3,
    const float* __restrict__ bn_g, const float* __restrict__ bn_b,
    const float* __restrict__ bn_m, const float* __restrict__ bn_v,
    float* __restrict__ g_out)
{
    __shared__ float ea[WAVES][EAF];

    const int tid = threadIdx.x;
    const int wid = tid >> 6;
    const int lane = tid & 63;
    const int half = lane >> 5;
    const int c = lane & 31;

    float* EA = ea[wid];
    float* DIS = EA + 656;
    short* TR = (short*)EA;
    const int g = blockIdx.x * WAVES + wid;

    const float* eag = edge_attr + (size_t)g * EPG;
#pragma unroll
    for (int j = 0; j < 10; ++j)
        gload_lds4(eag + 64 * j + lane, EA + 64 * j);
    if (lane < 10)
        gload_lds4(eag + 640 + lane, EA + 640);

    float Sc = 0.f, Tc = 0.f, bia[4] = {0.f, 0.f, 0.f, 0.f};
    if (c < FH) {
        const float s = bn_g[c] * rsqrtf(bn_v[c] + BN_EPS);
        Sc = s; Tc = bn_b[c] - bn_m[c] * s;
        bia[0] = b1[c]; bia[1] = b20[c]; bia[2] = b21[c]; bia[3] = b3[c];
    }

    Frag ha[2];
    {
        const int n = c;
        if (n < NODES) {
            const float* xr = x + ((size_t)g * NODES + n) * 26;
#pragma unroll
            for (int ks = 0; ks < 2; ++ks) {
#pragma unroll
                for (int t = 0; t < 4; ++t) {
                    const int k0 = ks * 16 + half * 8 + 2 * t;
                    float lo = 0.f, hi = 0.f;
                    if (k0 < 26) {
                        const float2 v = *(const float2*)(xr + k0);
                        lo = v.x; hi = v.y;
                    }
                    ha[ks].u[t] = pk2(lo, hi);
                }
            }
        } else {
            Frag z; z.u[0] = z.u[1] = z.u[2] = z.u[3] = 0;
            ha[0] = z; ha[1] = z;
        }
    }

    asm volatile("s_waitcnt vmcnt(0)" ::: "memory");

    if (lane < NODES) {
        float d = 0.f;
#pragma unroll
        for (int j = 0; j < 25; ++j) d += EA[lane * 25 + j];
        DIS[lane] = (d > 0.f) ? rsqrtf(d) : 0.f;
    }

    Frag la[2];
    {
        const int n = c;
        const float dn = (n < NODES) ? DIS[n] : 0.f;
#pragma unroll
        for (int ks = 0; ks < 2; ++ks) {
#pragma unroll
            for (int t = 0; t < 4; ++t) {
                float v2[2];
#pragma unroll
                for (int q = 0; q < 2; ++q) {
                    const int m = ks * 16 + half * 8 + 2 * t + q;
                    float val = 0.f;
                    if (n < NODES && m < NODES && m != n) {
                        const int eidx = m * 25 + n - (n > m ? 1 : 0);
                        val = -EA[eidx] * DIS[m] * dn;
                    }
                    v2[q] = val;
                }
                la[ks].u[t] = pk2(v2[0], v2[1]);
            }
        }
    }

    float h[16];
#pragma unroll
    for (int L = 0; L < 4; ++L) {
        const short8* wp = wpack + (size_t)L * 4 * 64;
        Frag wq0, wq1, wp0, wp1;
        wq0.v = wp[lane];
        wq1.v = wp[64 + lane];
        wp0.v = wp[128 + lane];
        wp1.v = wp[192 + lane];

        f32x16 Qc = {};
        f32x16 Pc = {};
        Qc = mfma32(ha[0].v, wq0.v, Qc);
        Pc = mfma32(ha[0].v, wp0.v, Pc);
        Qc = mfma32(ha[1].v, wq1.v, Qc);
        Pc = mfma32(ha[1].v, wp1.v, Pc);

        Frag pb0, pb1;
#pragma unroll
        for (int ks = 0; ks < 2; ++ks) {
            const int b = ks * 8;
            const unsigned u0 = pk2(Pc[b + 0], Pc[b + 1]);
            const unsigned u1 = pk2(Pc[b + 2], Pc[b + 3]);
            const unsigned v0 = pk2(Pc[b + 4], Pc[b + 5]);
            const unsigned v1 = pk2(Pc[b + 6], Pc[b + 7]);
            auto r0 = __builtin_amdgcn_permlane32_swap(u0, v0, false, false);
            auto r1 = __builtin_amdgcn_permlane32_swap(u1, v1, false, false);
            Frag& pb = ks ? pb1 : pb0;
            pb.u[0] = r0[0]; pb.u[2] = r0[1];
            pb.u[1] = r1[0]; pb.u[3] = r1[1];
        }
        Qc = mfma32(la[0].v, pb0.v, Qc);
        Qc = mfma32(la[1].v, pb1.v, Qc);

        const float bb = bia[L];
#pragma unroll
        for (int r = 0; r < 16; ++r) {
            float z = fmaxf(Qc[r] + bb, 0.f);
            z = z * Sc + Tc;
            h[r] = L ? fmaf(0.7f, h[r], z) : z;
        }

        if (L < 3) {
#pragma unroll
            for (int r = 0; r < 16; ++r) {
                const int n = (r & 3) + 8 * (r >> 2) + 4 * half;
                const int byte = (n * 64 + 2 * c) ^ ((n & 7) << 4);
                *(short*)((char*)TR + byte) = (short)f2bf(h[r]);
            }
#pragma unroll
            for (int ks = 0; ks < 2; ++ks) {
                const int byte = (c * 64 + ks * 32 + half * 16) ^ ((c & 7) << 4);
                Frag f; f.v = *(const short8*)((const char*)TR + byte);
                ha[ks] = f;
            }
        }
    }

#pragma unroll
    for (int r = 0; r < 16; ++r) {
        const int n = (r & 3) + 8 * (r >> 2) + 4 * half;
        if (n < NODES && c < FH) EA[n * FH + c] = h[r];
    }
    {
        const float4* EAv = (const float4*)EA;
        float4* gov = (float4*)(g_out + (size_t)g * GD);
#pragma unroll
        for (int jj = 0; jj < 3; ++jj) {
            const int i = lane + 64 * jj;
            if (i < 130) gov[i] = EAv[i];
        }
    }
}

// ---------------------------------------------------------------------------
// fc_mfma: out[16384][128] = G @ fc_w^T + fc_b via split-precision bf16 MFMA.
// One 32x32 output tile per wave; 512 blocks x 4 waves; NO LDS.
// g = hi+lo, w = whi+wlo (RNE residual split); acc += hi*whi + lo*whi + hi*wlo
// -> ~2^-18 relative operand error, f32-grade result.
// ---------------------------------------------------------------------------
__global__ __launch_bounds__(256) void fc_mfma(
    const float* __restrict__ G, const short8* __restrict__ wpack2,
    const float* __restrict__ fc_b, float* __restrict__ C)
{
    const int tid = threadIdx.x;
    const int wid = tid >> 6;            // = n-tile (0..3)
    const int lane = tid & 63;
    const int half = lane >> 5;
    const int c = lane & 31;

    const int mt = blockIdx.x;           // 0..511
    const int nt = wid;

    const float* ga = G + (size_t)(mt * 32 + c) * GD;   // this lane's A row
    f32x16 acc = {};

#pragma unroll 3
    for (int sp = 0; sp < 33; ++sp) {
        const int kb = sp * 16 + half * 8;
        float v[8];
        if (kb < GD) {                   // uniform per half; sp=32/half=1 -> pad
            const float4 q0 = *(const float4*)(ga + kb);
            const float4 q1 = *(const float4*)(ga + kb + 4);
            v[0] = q0.x; v[1] = q0.y; v[2] = q0.z; v[3] = q0.w;
            v[4] = q1.x; v[5] = q1.y; v[6] = q1.z; v[7] = q1.w;
        } else {
#pragma unroll
            for (int j = 0; j < 8; ++j) v[j] = 0.f;
        }
        Frag ahi, alo;
#pragma unroll
        for (int t = 0; t < 4; ++t) {
            const unsigned short s0 = f2bf(v[2 * t]);
            const unsigned short s1 = f2bf(v[2 * t + 1]);
            ahi.u[t] = (unsigned)s0 | ((unsigned)s1 << 16);
            const float r0 = v[2 * t]     - bf2f(s0);
            const float r1 = v[2 * t + 1] - bf2f(s1);
            alo.u[t] = pk2(r0, r1);
        }

        const short8* wb = wpack2 + ((size_t)(sp * 4 + nt) * 2) * 64;
        Frag whi, wlo;
        whi.v = wb[lane];
        wlo.v = wb[64 + lane];

        acc = mfma32(ahi.v, whi.v, acc);
        acc = mfma32(alo.v, whi.v, acc);
        acc = mfma32(ahi.v, wlo.v, acc);
    }

    const float bb = fc_b[nt * 32 + c];
#pragma unroll
    for (int r = 0; r < 16; ++r) {
        const int row = (r & 3) + 8 * (r >> 2) + 4 * half;
        C[(size_t)(mt * 32 + row) * 128 + nt * 32 + c] = acc[r] + bb;
    }
}

// ---------------------------------------------------------------------------
// graph_fb: round-7 passing kernel VERBATIM — fallback when workspace small.
// ---------------------------------------------------------------------------
template <bool FUSED_FC>
__global__ __launch_bounds__(512, 4) void graph_fb(
    const float* __restrict__ x,
    const float* __restrict__ edge_attr,
    const float* __restrict__ w1_0, const float* __restrict__ w1_1, const float* __restrict__ b1,
    const float* __restrict__ w20_0, const float* __restrict__ w20_1, const float* __restrict__ b20,
    const float* __restrict__ w21_0, const float* __restrict__ w21_1, const float* __restrict__ b21,
    const float* __restrict__ w3_0, const float* __restrict__ w3_1, const float* __restrict__ b3,
    const float* __restrict__ bn_g, const float* __restrict__ bn_b,
    const float* __restrict__ bn_m, const float* __restrict__ bn_v,
    float* __restrict__ g_out,
    const float* __restrict__ fc_w, const float* __restrict__ fc_b)
{
    __shared__ short8 wfrag[16 * 64];
    __shared__ float  ea[WAVES][EAF];

    const int tid = threadIdx.x;
    const int wid = tid >> 6;
    const int lane = tid & 63;
    const int half = lane >> 5;
    const int c = lane & 31;

    for (int e = tid; e < 16 * 64; e += 512) {
        const int fid = e >> 6, ln = e & 63;
        const int mat = fid >> 1, ks = fid & 1;
        const int cc = ln & 31, hf = ln >> 5;
        const int F = (mat < 2) ? 26 : 20;
        const float* Wp;
        switch (mat) {
            case 0: Wp = w1_0; break;  case 1: Wp = w1_1; break;
            case 2: Wp = w20_0; break; case 3: Wp = w20_1; break;
            case 4: Wp = w21_0; break; case 5: Wp = w21_1; break;
            case 6: Wp = w3_0; break;  default: Wp = w3_1; break;
        }
        Frag f;
#pragma unroll
        for (int t = 0; t < 4; ++t) {
            const int k0 = ks * 16 + hf * 8 + 2 * t;
            float lo = 0.f, hi = 0.f;
            if (cc < FH) {
                if (k0 < F)     lo = Wp[cc * F + k0];
                if (k0 + 1 < F) hi = Wp[cc * F + k0 + 1];
            }
            f.u[t] = pk2(lo, hi);
        }
        wfrag[e] = f.v;
    }

    float Sc = 0.f, Tc = 0.f, bia[4] = {0.f, 0.f, 0.f, 0.f};
    if (c < FH) {
        const float s = bn_g[c] * rsqrtf(bn_v[c] + BN_EPS);
        Sc = s; Tc = bn_b[c] - bn_m[c] * s;
        bia[0] = b1[c]; bia[1] = b20[c]; bia[2] = b21[c]; bia[3] = b3[c];
    }

    __syncthreads();

    float* EA = ea[wid];
    float* DIS = EA + 656;
    short* TR = (short*)EA;
    const int g = blockIdx.x * WAVES + wid;

    const float* eag = edge_attr + (size_t)g * EPG;
    for (int i = lane; i < EPG; i += 64) EA[i] = eag[i];

    if (lane < NODES) {
        float d = 0.f;
#pragma unroll
        for (int j = 0; j < 25; ++j) d += EA[lane * 25 + j];
        DIS[lane] = (d > 0.f) ? rsqrtf(d) : 0.f;
    }

    Frag la[2];
    {
        const int n = c;
        const float dn = (n < NODES) ? DIS[n] : 0.f;
#pragma unroll
        for (int ks = 0; ks < 2; ++ks) {
#pragma unroll
            for (int t = 0; t < 4; ++t) {
                float v2[2];
#pragma unroll
                for (int q = 0; q < 2; ++q) {
                    const int m = ks * 16 + half * 8 + 2 * t + q;
                    float val = 0.f;
                    if (n < NODES && m < NODES && m != n) {
                        const int eidx = m * 25 + n - (n > m ? 1 : 0);
                        val = -EA[eidx] * DIS[m] * dn;
                    }
                    v2[q] = val;
                }
                la[ks].u[t] = pk2(v2[0], v2[1]);
            }
        }
    }

    Frag ha[2];
    {
        const int n = c;
        if (n < NODES) {
            const float* xr = x + ((size_t)g * NODES + n) * 26;
#pragma unroll
            for (int ks = 0; ks < 2; ++ks) {
#pragma unroll
                for (int t = 0; t < 4; ++t) {
                    const int k0 = ks * 16 + half * 8 + 2 * t;
                    float lo = 0.f, hi = 0.f;
                    if (k0 < 26) {
                        const float2 v = *(const float2*)(xr + k0);
                        lo = v.x; hi = v.y;
                    }
                    ha[ks].u[t] = pk2(lo, hi);
                }
            }
        } else {
            Frag z; z.u[0] = z.u[1] = z.u[2] = z.u[3] = 0;
            ha[0] = z; ha[1] = z;
        }
    }

    float h[16];
#pragma unroll
    for (int L = 0; L < 4; ++L) {
        Frag wq0, wq1, wp0, wp1;
        wq0.v = wfrag[((L * 2 + 0) * 2 + 0) * 64 + lane];
        wq1.v = wfrag[((L * 2 + 0) * 2 + 1) * 64 + lane];
        wp0.v = wfrag[((L * 2 + 1) * 2 + 0) * 64 + lane];
        wp1.v = wfrag[((L * 2 + 1) * 2 + 1) * 64 + lane];

        f32x16 Qc = {};
        f32x16 Pc = {};
        Qc = mfma32(ha[0].v, wq0.v, Qc);
        Pc = mfma32(ha[0].v, wp0.v, Pc);
        Qc = mfma32(ha[1].v, wq1.v, Qc);
        Pc = mfma32(ha[1].v, wp1.v, Pc);

        Frag pb0, pb1;
#pragma unroll
        for (int ks = 0; ks < 2; ++ks) {
            const int b = ks * 8;
            const unsigned u0 = pk2(Pc[b + 0], Pc[b + 1]);
            const unsigned u1 = pk2(Pc[b + 2], Pc[b + 3]);
            const unsigned v0 = pk2(Pc[b + 4], Pc[b + 5]);
            const unsigned v1 = pk2(Pc[b + 6], Pc[b + 7]);
            auto r0 = __builtin_amdgcn_permlane32_swap(u0, v0, false, false);
            auto r1 = __builtin_amdgcn_permlane32_swap(u1, v1, false, false);
            Frag& pb = ks ? pb1 : pb0;
            pb.u[0] = r0[0]; pb.u[2] = r0[1];
            pb.u[1] = r1[0]; pb.u[3] = r1[1];
        }
        Qc = mfma32(la[0].v, pb0.v, Qc);
        Qc = mfma32(la[1].v, pb1.v, Qc);

        const float bb = bia[L];
#pragma unroll
        for (int r = 0; r < 16; ++r) {
            float z = fmaxf(Qc[r] + bb, 0.f);
            z = z * Sc + Tc;
            h[r] = L ? fmaf(0.7f, h[r], z) : z;
        }

        if (L < 3) {
#pragma unroll
            for (int r = 0; r < 16; ++r) {
                const int n = (r & 3) + 8 * (r >> 2) + 4 * half;
                const int byte = (n * 64 + 2 * c) ^ ((n & 7) << 4);
                *(short*)((char*)TR + byte) = (short)f2bf(h[r]);
            }
#pragma unroll
            for (int ks = 0; ks < 2; ++ks) {
                const int byte = (c * 64 + ks * 32 + half * 16) ^ ((c & 7) << 4);
                Frag f; f.v = *(const short8*)((const char*)TR + byte);
                ha[ks] = f;
            }
        }
    }

#pragma unroll
    for (int r = 0; r < 16; ++r) {
        const int n = (r & 3) + 8 * (r >> 2) + 4 * half;
        if (n < NODES && c < FH) EA[n * FH + c] = h[r];
    }

    if constexpr (!FUSED_FC) {
        float* go = g_out + (size_t)g * GD;
        for (int i = lane; i < GD; i += 64) go[i] = EA[i];
    } else {
#pragma unroll
        for (int oo = 0; oo < 2; ++oo) {
            const int o = lane + oo * 64;
            float dot = fc_b[o];
            const float* wr = fc_w + (size_t)o * GD;
            for (int i = 0; i < GD; ++i) dot = fmaf(EA[i], wr[i], dot);
            g_out[(size_t)g * 128 + o] = dot;
        }
    }
}

// ---------------------------------------------------------------------------
// fc_kernel: f32 fallback FC (round-12 version, BM64xBN128).
// ---------------------------------------------------------------------------
#define BM 64
#define BNN 128
#define BK 40

__global__ __launch_bounds__(256) void fc_kernel(
    const float* __restrict__ G, const float* __restrict__ W,
    const float* __restrict__ bias, float* __restrict__ C)
{
    __shared__ float Al[BK][BM + 4];
    __shared__ float Bl[BK][BNN];
    const int tid = threadIdx.x;
    const int m0 = blockIdx.x * BM;
    const int tr = tid >> 5;
    const int tc = tid & 31;
    const int r0 = tr * 8, c0 = tc * 4;
    float acc[8][4] = {};

    const int arow = tid >> 2;
    const int aq   = tid & 3;
    const int brow = tid >> 1;
    const int bh   = tid & 1;

    for (int kt = 0; kt < GD; kt += BK) {
        __syncthreads();
        {
            const float* ga = G + (size_t)(m0 + arow) * GD + kt + aq * 10;
#pragma unroll
            for (int j = 0; j < 10; ++j) Al[aq * 10 + j][arow] = ga[j];
            const float* gb = W + (size_t)brow * GD + kt + bh * 20;
#pragma unroll
            for (int j = 0; j < 20; ++j) Bl[bh * 20 + j][brow] = gb[j];
        }
        __syncthreads();
#pragma unroll 4
        for (int k = 0; k < BK; ++k) {
            float4 a01 = *reinterpret_cast<const float4*>(&Al[k][r0]);
            float4 a23 = *reinterpret_cast<const float4*>(&Al[k][r0 + 4]);
            float4 b   = *reinterpret_cast<const float4*>(&Bl[k][c0]);
            float av[8] = {a01.x, a01.y, a01.z, a01.w, a23.x, a23.y, a23.z, a23.w};
#pragma unroll
            for (int i = 0; i < 8; ++i) {
                acc[i][0] = fmaf(av[i], b.x, acc[i][0]);
                acc[i][1] = fmaf(av[i], b.y, acc[i][1]);
                acc[i][2] = fmaf(av[i], b.z, acc[i][2]);
                acc[i][3] = fmaf(av[i], b.w, acc[i][3]);
            }
        }
    }

    const float4 bb = *reinterpret_cast<const float4*>(&bias[c0]);
#pragma unroll
    for (int i = 0; i < 8; ++i) {
        float4 o;
        o.x = acc[i][0] + bb.x;
        o.y = acc[i][1] + bb.y;
        o.z = acc[i][2] + bb.z;
        o.w = acc[i][3] + bb.w;
        *reinterpret_cast<float4*>(&C[(size_t)(m0 + r0 + i) * 128 + c0]) = o;
    }
}

// ---------------------------------------------------------------------------

extern "C" void kernel_launch(void* const* d_in, const int* in_sizes, int n_in,
                              void* d_out, int out_size, void* d_ws, size_t ws_size,
                              hipStream_t stream)
{
    const float* x        = (const float*)d_in[0];
    const float* edge_attr= (const float*)d_in[2];
    const float* w1_0  = (const float*)d_in[4];
    const float* w1_1  = (const float*)d_in[5];
    const float* b1    = (const float*)d_in[6];
    const float* w20_0 = (const float*)d_in[7];
    const float* w20_1 = (const float*)d_in[8];
    const float* b20   = (const float*)d_in[9];
    const float* w21_0 = (const float*)d_in[10];
    const float* w21_1 = (const float*)d_in[11];
    const float* b21   = (const float*)d_in[12];
    const float* w3_0  = (const float*)d_in[13];
    const float* w3_1  = (const float*)d_in[14];
    const float* b3    = (const float*)d_in[15];
    const float* bn_g  = (const float*)d_in[16];
    const float* bn_b  = (const float*)d_in[17];
    const float* bn_m  = (const float*)d_in[18];
    const float* bn_v  = (const float*)d_in[19];
    const float* fc_w  = (const float*)d_in[20];
    const float* fc_b  = (const float*)d_in[21];
    float* out = (float*)d_out;

    const size_t need_g = (size_t)NGRAPH * GD * sizeof(float);

    if (ws_size >= need_g + WS_HDR) {
        short8* wpack  = (short8*)d_ws;
        short8* wpack2 = (short8*)((char*)d_ws + WPACK_BYTES);
        float*  gbuf   = (float*)((char*)d_ws + WS_HDR);
        hipLaunchKernelGGL(prepack_all, dim3(70), dim3(256), 0, stream,
                           w1_0, w1_1, w20_0, w20_1, w21_0, w21_1, w3_0, w3_1,
                           fc_w, wpack, wpack2);
        hipLaunchKernelGGL(graph_wp, dim3(NGRAPH / WAVES), dim3(512), 0, stream,
                           x, edge_attr, wpack, b1, b20, b21, b3,
                           bn_g, bn_b, bn_m, bn_v, gbuf);
        hipLaunchKernelGGL(fc_mfma, dim3(NGRAPH / 32), dim3(256), 0, stream,
                           gbuf, wpack2, fc_b, out);
    } else if (ws_size >= need_g) {
        float* gbuf = (float*)d_ws;
        hipLaunchKernelGGL((graph_fb<false>), dim3(NGRAPH / WAVES), dim3(512), 0, stream,
                           x, edge_attr, w1_0, w1_1, b1, w20_0, w20_1, b20,
                           w21_0, w21_1, b21, w3_0, w3_1, b3,
                           bn_g, bn_b, bn_m, bn_v, gbuf, fc_w, fc_b);
        hipLaunchKernelGGL(fc_kernel, dim3(NGRAPH / BM), dim3(256), 0, stream,
                           gbuf, fc_w, fc_b, out);
    } else {
        hipLaunchKernelGGL((graph_fb<true>), dim3(NGRAPH / WAVES), dim3(512), 0, stream,
                           x, edge_attr, w1_0, w1_1, b1, w20_0, w20_1, b20,
                           w21_0, w21_1, b21, w3_0, w3_1, b3,
                           bn_g, bn_b, bn_m, bn_v, out, fc_w, fc_b);
    }
}